// Round 2
// baseline (457.308 us; speedup 1.0000x reference)
//
#include <hip/hip_runtime.h>

// Problem constants: b=1, m=128, n=256, c=22
#define NC 22
#define NCC (NC*NC)          // 484 floats per (i,j) coupling tile
#define NJ 256
#define NI 256
#define NM 128
#define JG 8                 // j's per quarter per superstep
#define NQ 4                 // intra-block j-split (quarters)
#define SS (NJ/(NQ*JG))      // 8 supersteps
#define TILEF (NQ*JG*NCC)    // 15488 floats = 61952 B (single-buffered)
#define TILE4 (TILEF/4)      // 3872 float4
#define RPT 4                // staging rounds: ceil(3872/1024)

// hi[m,i,c] = sum_j eij[i,j,c,v[m,j]] * mask_vec[v[m,j]]
// motifs[m,i,c] = ei[i,c] + hi[m,i,c];  logits[m,i] = motifs[m,i,v[m,i]]
// Block = one i, 1024 threads = (q:4) x (half:2) x (m:128) -> 16 waves/CU,
// 4 waves/SIMD (vs 1 in R1 -- the latency-hiding fix).
__global__ __launch_bounds__(1024, 4) void potts_main(
    const int*   __restrict__ variant,   // [128,256] int32
    const float* __restrict__ eij,       // [256,256,22,22]
    const float* __restrict__ ei,        // [256,22]
    const float* __restrict__ mask_vec,  // [22]
    float*       __restrict__ out_motifs,// [128,256,22]
    float*       __restrict__ out_logits)// [128,256]
{
    const int i    = blockIdx.x;
    const int tid  = threadIdx.x;
    const int q    = tid >> 8;           // j-quarter 0..3
    const int half = (tid >> 7) & 1;     // c-half
    const int m    = tid & 127;
    const int cc0  = half * 11;

    __shared__ float lds[TILEF];         // 61952 B; reused for reduction

    // Staging map. Flat float4 index f = r*1024+tid covers the whole tile.
    // 484 = 4*121 and per-q subtile = 968 float4, so a float4 never straddles
    // a j or q boundary. Decompose f -> (fq, j_local, cd4) once; per superstep
    // only the global base advances by 968 float4.
    int   g4[RPT];
    float mreg[RPT][4];
    bool  act[RPT];
    #pragma unroll
    for (int r = 0; r < RPT; ++r) {
        const int f = r * 1024 + tid;
        act[r] = (f < TILE4);
        const int fc = act[r] ? f : 0;
        const int fq = fc / 968;         // which quarter's subtile
        const int fr = fc % 968;
        const int jl = fr / 121;         // j within subtile
        const int cd4 = fr % 121;        // float4 within [c][d] row
        g4[r] = (fq * 64 + jl) * 121 + cd4;   // float4 offset in row-i block (s=0)
        #pragma unroll
        for (int t = 0; t < 4; ++t)
            mreg[r][t] = act[r] ? mask_vec[(4 * cd4 + t) % NC] : 0.f;
    }

    const float4* gsrc = (const float4*)eij + (size_t)i * (NJ * NCC / 4);

    float acc[11];
    #pragma unroll
    for (int k = 0; k < 11; ++k) acc[k] = 0.f;

    // Register prefetch of superstep 0
    float4 pf[RPT];
    #pragma unroll
    for (int r = 0; r < RPT; ++r)
        if (act[r]) pf[r] = gsrc[g4[r]];

    for (int s = 0; s < SS; ++s) {
        if (s) __syncthreads();          // previous gather reads done

        // LDS write, mask folded, lane-linear float4 (conflict-free)
        #pragma unroll
        for (int r = 0; r < RPT; ++r) {
            if (act[r]) {
                float4 v = pf[r];
                v.x *= mreg[r][0]; v.y *= mreg[r][1];
                v.z *= mreg[r][2]; v.w *= mreg[r][3];
                ((float4*)lds)[r * 1024 + tid] = v;
            }
        }
        __syncthreads();

        // Prefetch next superstep (overlaps the gather below)
        if (s + 1 < SS) {
            const float4* gn = gsrc + (size_t)(s + 1) * 968;
            #pragma unroll
            for (int r = 0; r < RPT; ++r)
                if (act[r]) pf[r] = gn[g4[r]];
        }

        // This quarter's 8 j's
        const int j0 = q * 64 + s * JG;
        const int4 va = *(const int4*)(variant + m * NJ + j0);
        const int4 vb = *(const int4*)(variant + m * NJ + j0 + 4);
        const int vs[JG] = {va.x, va.y, va.z, va.w, vb.x, vb.y, vb.z, vb.w};

        // Gather: addr = wave-uniform base + v (v in [0,22)) -> <=22 distinct
        // banks, conflict-free; offsets k*88B pair into ds_read2_b32.
        const float* tb = lds + q * (JG * NCC) + cc0 * NC;
        #pragma unroll
        for (int jj = 0; jj < JG; ++jj) {
            const float* p = tb + jj * NCC + vs[jj];
            #pragma unroll
            for (int k = 0; k < 11; ++k)
                acc[k] += p[k * NC];
        }
    }

    // Reduce partial acc over q through LDS (reuse tile; 256*44 floats fit)
    __syncthreads();
    float* red = lds;
    #pragma unroll
    for (int k = 0; k < 11; ++k)
        red[(half * 128 + m) * 44 + q * 11 + k] = acc[k];
    __syncthreads();

    if (tid < 256) {
        const int mm = tid & 127;
        const int hh = tid >> 7;
        const int c0 = hh * 11;
        const float* base  = lds + (hh * 128 + mm) * 44;
        const float* eirow = ei + i * NC;
        float* mout = out_motifs + ((size_t)mm * NI + i) * NC;
        const int vi = variant[mm * NJ + i];
        float logit = 0.f;
        #pragma unroll
        for (int k = 0; k < 11; ++k) {
            const float v = base[k] + base[11 + k] + base[22 + k] + base[33 + k]
                          + eirow[c0 + k];
            mout[c0 + k] = v;
            if (c0 + k == vi) logit = v;
        }
        if (vi >= c0 && vi < c0 + 11)
            out_logits[mm * NI + i] = logit;
    }
}

// variant_logit[m] = sigma * sum_i (logits[m,i]-logits[0,i]) * vm[m,i]*vm[0,i]
__global__ __launch_bounds__(64) void potts_pool(
    const float* __restrict__ logits,  // [128,256]
    const float* __restrict__ vmask,   // [128,256]
    const float* __restrict__ sigma,   // [1]
    float*       __restrict__ out_vl)  // [128]
{
    const int m    = blockIdx.x;
    const int lane = threadIdx.x;
    float s = 0.f;
    #pragma unroll
    for (int qq = 0; qq < 4; ++qq) {
        const int i = lane + 64 * qq;
        const float vl = logits[m * NI + i] - logits[i];
        s += vl * vmask[m * NI + i] * vmask[i];
    }
    #pragma unroll
    for (int off = 32; off > 0; off >>= 1)
        s += __shfl_down(s, off, 64);
    if (lane == 0) out_vl[m] = sigma[0] * s;
}

extern "C" void kernel_launch(void* const* d_in, const int* in_sizes, int n_in,
                              void* d_out, int out_size, void* d_ws, size_t ws_size,
                              hipStream_t stream) {
    const int*   variant  = (const int*)  d_in[0];  // [1,128,256] int32
    const float* vmask    = (const float*)d_in[1];  // [1,128,256]
    const float* eij      = (const float*)d_in[2];  // [1,256,256,22,22]
    const float* ei       = (const float*)d_in[3];  // [1,256,22]
    const float* mask_vec = (const float*)d_in[4];  // [22]
    const float* sigma    = (const float*)d_in[5];  // [1]

    float* out        = (float*)d_out;
    float* out_motifs = out;                        // 128*256*22
    float* out_logits = out_motifs + NM * NI * NC;  // 128*256
    float* out_vl     = out_logits + NM * NI;       // 128

    potts_main<<<NI, 1024, 0, stream>>>(variant, eij, ei, mask_vec,
                                        out_motifs, out_logits);
    potts_pool<<<NM, 64, 0, stream>>>(out_logits, vmask, sigma, out_vl);
}